// Round 13
// baseline (643.140 us; speedup 1.0000x reference)
//
#include <hip/hip_runtime.h>
#include <hip/hip_bf16.h>

#define L_SEQ   4096
#define DMODEL  1024
#define DINNER  2048
#define DSTATE  64
#define NB      2
#define DPBS    64           // d-channels per scan block (SPLIT=4: 256 thr = 64 d x 4 qtr)
#define DBCS    2304         // dbc row stride (B|C|dt|pad)
#define NROWS   (NB * L_SEQ) // 8192

typedef unsigned short u16;
typedef __attribute__((ext_vector_type(8))) short bf16x8;
typedef __attribute__((ext_vector_type(4))) float f32x4;
typedef __attribute__((ext_vector_type(2))) float f32x2;

__device__ __forceinline__ float silu_f(float x)  { return x / (1.f + __expf(-x)); }
__device__ __forceinline__ float softplus_f(float x) {
    return x > 15.f ? x : __logf(1.f + __expf(x));
}
__device__ __forceinline__ float bf2f(u16 u) { return __uint_as_float(((unsigned)u) << 16); }
__device__ __forceinline__ u16 f2bf(float f) {
    __hip_bfloat16 h = __float2bfloat16(f);
    return *reinterpret_cast<u16*>(&h);
}
__device__ __forceinline__ unsigned pack2(float a, float b) {
    return (unsigned)f2bf(a) | ((unsigned)f2bf(b) << 16);
}

// ---------------- fp32 -> bf16 elementwise convert -------------------------------------
__global__ __launch_bounds__(256) void f32_to_bf16_kernel(
    const float* __restrict__ in, u16* __restrict__ out)
{
    const int i = (blockIdx.x * 256 + threadIdx.x) * 4;
    float4 v = *reinterpret_cast<const float4*>(in + i);
    ushort4 o;
    o.x = f2bf(v.x); o.y = f2bf(v.y); o.z = f2bf(v.z); o.w = f2bf(v.w);
    *reinterpret_cast<ushort4*>(out + i) = o;
}

// ---------------- W[K][N] fp32 -> Wt[N][K] bf16 (tiled transpose) ----------------------
__global__ __launch_bounds__(256) void transpose_bf16_kernel(
    const float* __restrict__ W, u16* __restrict__ Wt, int K, int N)
{
    __shared__ float t[32][33];
    const int n0 = blockIdx.x * 32, k0 = blockIdx.y * 32;
    const int tx = threadIdx.x & 31, ty = threadIdx.x >> 5;   // ty 0..7
    #pragma unroll
    for (int i = 0; i < 32; i += 8)
        t[ty + i][tx] = W[(size_t)(k0 + ty + i) * N + n0 + tx];
    __syncthreads();
    #pragma unroll
    for (int i = 0; i < 32; i += 8)
        Wt[(size_t)(n0 + ty + i) * K + k0 + tx] = f2bf(t[tx][ty + i]);
}

// ---------------- build [0_128 | b_dt | 0_pad] bias vector -----------------------------
__global__ __launch_bounds__(256) void bias_cat_kernel(
    const float* __restrict__ b_dt, float* __restrict__ bias)
{
    const int i = blockIdx.x * 256 + threadIdx.x;   // 0..2303
    float v = 0.f;
    if (i >= 128 && i < 128 + DINNER) v = b_dt[i - 128];
    bias[i] = v;
}

// ---------------- A-structure precompute: A0[d], ok[d] ---------------------------------
__global__ __launch_bounds__(256) void a0_kernel(
    const float* __restrict__ A_log, float* __restrict__ A0f,
    unsigned char* __restrict__ okf)
{
    const int d = blockIdx.x * 256 + threadIdx.x;   // 2048 threads
    const float A0 = -__expf(A_log[d * DSTATE]);
    int ok = 1;
    for (int s = 1; s < DSTATE; ++s) {
        const float As = -__expf(A_log[d * DSTATE + s]);
        ok &= (fabsf(As - A0 * (float)(s + 1)) <= 1e-3f * (float)(s + 1));
    }
    A0f[d] = A0;
    okf[d] = (unsigned char)ok;
}

// ---------------- 128x128 bf16 MFMA GEMM (m97 structure + XCD swizzle) -----------------
template <typename TC>
__global__ __launch_bounds__(256) void mfma_gemm(
    const u16* __restrict__ A, int lda,      // [M][K] bf16
    const u16* __restrict__ Bt, int ldb,     // [N][K] bf16
    TC* __restrict__ C, int ldc,
    int K, const float* __restrict__ bias)
{
    __shared__ u16 As[128 * 32];
    __shared__ u16 Bs[128 * 32];
    const int tid  = threadIdx.x;
    const int lane = tid & 63;
    const int w    = tid >> 6;
    const int wm   = w >> 1, wn = w & 1;

    const int gx = gridDim.x;
    const int nwg = gx * gridDim.y;
    int wg = blockIdx.y * gx + blockIdx.x;
    if ((nwg & 7) == 0) wg = (wg & 7) * (nwg >> 3) + (wg >> 3);
    const int bm = (wg / gx) * 128, bn = (wg % gx) * 128;

    const int lr = lane & 15, lk = lane >> 4;
    const int srow  = lane >> 2;
    const int scolb = (lane & 3) * 16;
    const size_t ldaB = (size_t)lda * 2, ldbB = (size_t)ldb * 2;

    const char* Ab = (const char*)A + (size_t)bm * ldaB;
    const char* Bb = (const char*)Bt + (size_t)bn * ldbB;
    char* AsB = (char*)As;
    char* BsB = (char*)Bs;

    f32x4 acc[4][4] = {};

    for (int k0 = 0; k0 < K; k0 += 32) {
        const size_t kb = (size_t)k0 * 2;
        #pragma unroll
        for (int i = 0; i < 2; ++i) {
            const int row = i * 64 + w * 16 + srow;
            __builtin_amdgcn_global_load_lds(
                (const __attribute__((address_space(1))) void*)(Ab + (size_t)row * ldaB + kb + scolb),
                (__attribute__((address_space(3))) void*)(AsB + i * 4096 + w * 1024),
                16, 0, 0);
            __builtin_amdgcn_global_load_lds(
                (const __attribute__((address_space(1))) void*)(Bb + (size_t)row * ldbB + kb + scolb),
                (__attribute__((address_space(3))) void*)(BsB + i * 4096 + w * 1024),
                16, 0, 0);
        }
        __syncthreads();
        bf16x8 a[4], b[4];
        #pragma unroll
        for (int mi = 0; mi < 4; ++mi)
            a[mi] = *reinterpret_cast<const bf16x8*>(&As[(wm * 64 + mi * 16 + lr) * 32 + lk * 8]);
        #pragma unroll
        for (int ni = 0; ni < 4; ++ni)
            b[ni] = *reinterpret_cast<const bf16x8*>(&Bs[(wn * 64 + ni * 16 + lr) * 32 + lk * 8]);
        #pragma unroll
        for (int mi = 0; mi < 4; ++mi)
            #pragma unroll
            for (int ni = 0; ni < 4; ++ni)
                acc[mi][ni] = __builtin_amdgcn_mfma_f32_16x16x32_bf16(a[mi], b[ni], acc[mi][ni], 0, 0, 0);
        __syncthreads();
    }

    float bv[4];
    if (bias) {
        #pragma unroll
        for (int ni = 0; ni < 4; ++ni) bv[ni] = bias[bn + wn * 64 + ni * 16 + lr];
    }
    #pragma unroll
    for (int mi = 0; mi < 4; ++mi) {
        #pragma unroll
        for (int ni = 0; ni < 4; ++ni) {
            #pragma unroll
            for (int r = 0; r < 4; ++r) {
                const int row = bm + wm * 64 + mi * 16 + lk * 4 + r;
                const int col = bn + wn * 64 + ni * 16 + lr;
                float v = acc[mi][ni][r];
                if (bias) v += bv[ni];
                if constexpr (sizeof(TC) == 4) C[(size_t)row * ldc + col] = v;
                else                           C[(size_t)row * ldc + col] = f2bf(v);
            }
        }
    }
}

// ---------------- 256x256 BK=64 8-phase bf16 MFMA GEMM (T2+T3+T4+T5) -------------------
// ACT: 0 = none, 2 = softplus on cols >= 128 (fused dt activation).
#define BAR()  asm volatile("s_barrier" ::: "memory")
#define WV(n)  asm volatile("s_waitcnt vmcnt(" #n ")" ::: "memory")
#define STG16(s, d) __builtin_amdgcn_global_load_lds( \
    (const __attribute__((address_space(1))) void*)(s), \
    (__attribute__((address_space(3))) void*)(d), 16, 0, 0)

template <typename TC, int ACT>
__global__ __launch_bounds__(512, 2) void gemm256(
    const u16* __restrict__ A, int lda,      // [M][K] bf16
    const u16* __restrict__ Bt, int ldb,     // [N][K] bf16
    TC* __restrict__ C, int ldc,
    int K, const float* __restrict__ bias)
{
    extern __shared__ char lds[];            // 131072 B
    const int tid = threadIdx.x;
    const int l = tid & 63, w = tid >> 6;
    const int wm = w >> 2, wn = w & 3;
    const int lr = l & 15, lk = l >> 4;

    const int gx = gridDim.x;
    const int nwg = gx * gridDim.y;
    int wg = blockIdx.y * gx + blockIdx.x;
    wg = (wg & 7) * (nwg >> 3) + (wg >> 3);  // all grids %8==0
    const int bm = (wg / gx) * 256, bn = (wg % gx) * 256;

    const size_t ldaB = (size_t)lda * 2, ldbB = (size_t)ldb * 2;
    const int gsw = (((l & 7) ^ (l >> 3)) << 4);
    const char* aSrc = (const char*)A + (size_t)(bm + w * 8 + (l >> 3)) * ldaB + gsw;
    const char* bSrc = (const char*)Bt + (size_t)(bn + w * 8 + (l >> 3)) * ldbB + gsw;
    const int csw0 = (lk * 16) ^ ((lr & 7) << 4);
    const int wdst = w * 1024;

    const int nk = K >> 6;
    f32x4 acc[8][4] = {};

    {
        STG16(aSrc + (size_t)(0 * 64) * ldaB, lds + 0 * 8192 + wdst);
        STG16(aSrc + (size_t)(2 * 64) * ldaB, lds + 2 * 8192 + wdst);
        STG16(bSrc + (size_t)(0 * 64) * ldbB, lds + 32768 + 0 * 8192 + wdst);
        STG16(bSrc + (size_t)(1 * 64) * ldbB, lds + 32768 + 1 * 8192 + wdst);
        STG16(bSrc + (size_t)(2 * 64) * ldbB, lds + 32768 + 2 * 8192 + wdst);
        STG16(bSrc + (size_t)(3 * 64) * ldbB, lds + 32768 + 3 * 8192 + wdst);
        STG16(aSrc + (size_t)(1 * 64) * ldaB, lds + 1 * 8192 + wdst);
        STG16(aSrc + (size_t)(3 * 64) * ldaB, lds + 3 * 8192 + wdst);
        WV(2);
        BAR();
    }

    for (int t = 0; t < nk; ++t) {
        const int p = t & 1;
        const char* Ar = lds + (p << 16);
        const char* Br = Ar + 32768;
        const int tn = (t + 1 < nk) ? t + 1 : t;
        char* dq = lds + (((t + 1) & 1) << 16);
        const size_t Tb = (size_t)tn << 7;
        const char* aS = aSrc + Tb;
        const char* bS = bSrc + Tb;

        bf16x8 a[4][2], bf[2][2];

        // ---- PH0 ----
        #pragma unroll
        for (int mi = 0; mi < 4; ++mi) {
            const int ro = (wm * 128 + mi * 16 + lr) * 128;
            a[mi][0] = *reinterpret_cast<const bf16x8*>(Ar + ro + csw0);
            a[mi][1] = *reinterpret_cast<const bf16x8*>(Ar + ro + (csw0 ^ 64));
        }
        #pragma unroll
        for (int ni = 0; ni < 2; ++ni) {
            const int ro = (wn * 64 + ni * 16 + lr) * 128;
            bf[ni][0] = *reinterpret_cast<const bf16x8*>(Br + ro + csw0);
            bf[ni][1] = *reinterpret_cast<const bf16x8*>(Br + ro + (csw0 ^ 64));
        }
        STG16(aS + (size_t)(0 * 64) * ldaB, dq + 0 * 8192 + wdst);
        STG16(aS + (size_t)(2 * 64) * ldaB, dq + 2 * 8192 + wdst);
        BAR();
        __builtin_amdgcn_s_setprio(1);
        #pragma unroll
        for (int mi = 0; mi < 4; ++mi)
            #pragma unroll
            for (int ni = 0; ni < 2; ++ni) {
                acc[mi][ni] = __builtin_amdgcn_mfma_f32_16x16x32_bf16(a[mi][0], bf[ni][0], acc[mi][ni], 0, 0, 0);
                acc[mi][ni] = __builtin_amdgcn_mfma_f32_16x16x32_bf16(a[mi][1], bf[ni][1], acc[mi][ni], 0, 0, 0);
            }
        __builtin_amdgcn_s_setprio(0);
        BAR();

        // ---- PH1 ----
        #pragma unroll
        for (int ni = 0; ni < 2; ++ni) {
            const int ro = (wn * 64 + (2 + ni) * 16 + lr) * 128;
            bf[ni][0] = *reinterpret_cast<const bf16x8*>(Br + ro + csw0);
            bf[ni][1] = *reinterpret_cast<const bf16x8*>(Br + ro + (csw0 ^ 64));
        }
        STG16(bS + (size_t)(0 * 64) * ldbB, dq + 32768 + 0 * 8192 + wdst);
        STG16(bS + (size_t)(1 * 64) * ldbB, dq + 32768 + 1 * 8192 + wdst);
        BAR();
        __builtin_amdgcn_s_setprio(1);
        #pragma unroll
        for (int mi = 0; mi < 4; ++mi)
            #pragma unroll
            for (int ni = 0; ni < 2; ++ni) {
                acc[mi][2 + ni] = __builtin_amdgcn_mfma_f32_16x16x32_bf16(a[mi][0], bf[ni][0], acc[mi][2 + ni], 0, 0, 0);
                acc[mi][2 + ni] = __builtin_amdgcn_mfma_f32_16x16x32_bf16(a[mi][1], bf[ni][1], acc[mi][2 + ni], 0, 0, 0);
            }
        __builtin_amdgcn_s_setprio(0);
        WV(4);
        BAR();

        // ---- PH2 ----
        #pragma unroll
        for (int mi = 0; mi < 4; ++mi) {
            const int ro = (wm * 128 + (4 + mi) * 16 + lr) * 128;
            a[mi][0] = *reinterpret_cast<const bf16x8*>(Ar + ro + csw0);
            a[mi][1] = *reinterpret_cast<const bf16x8*>(Ar + ro + (csw0 ^ 64));
        }
        STG16(bS + (size_t)(2 * 64) * ldbB, dq + 32768 + 2 * 8192 + wdst);
        STG16(bS + (size_t)(3 * 64) * ldbB, dq + 32768 + 3 * 8192 + wdst);
        BAR();
        __builtin_amdgcn_s_setprio(1);
        #pragma unroll
        for (int mi = 0; mi < 4; ++mi)
            #pragma unroll
            for (int ni = 0; ni < 2; ++ni) {
                acc[4 + mi][2 + ni] = __builtin_amdgcn_mfma_f32_16x16x32_bf16(a[mi][0], bf[ni][0], acc[4 + mi][2 + ni], 0, 0, 0);
                acc[4 + mi][2 + ni] = __builtin_amdgcn_mfma_f32_16x16x32_bf16(a[mi][1], bf[ni][1], acc[4 + mi][2 + ni], 0, 0, 0);
            }
        __builtin_amdgcn_s_setprio(0);
        BAR();

        // ---- PH3 ----
        #pragma unroll
        for (int ni = 0; ni < 2; ++ni) {
            const int ro = (wn * 64 + ni * 16 + lr) * 128;
            bf[ni][0] = *reinterpret_cast<const bf16x8*>(Br + ro + csw0);
            bf[ni][1] = *reinterpret_cast<const bf16x8*>(Br + ro + (csw0 ^ 64));
        }
        STG16(aS + (size_t)(1 * 64) * ldaB, dq + 1 * 8192 + wdst);
        STG16(aS + (size_t)(3 * 64) * ldaB, dq + 3 * 8192 + wdst);
        BAR();
        __builtin_amdgcn_s_setprio(1);
        #pragma unroll
        for (int mi = 0; mi < 4; ++mi)
            #pragma unroll
            for (int ni = 0; ni < 2; ++ni) {
                acc[4 + mi][ni] = __builtin_amdgcn_mfma_f32_16x16x32_bf16(a[mi][0], bf[ni][0], acc[4 + mi][ni], 0, 0, 0);
                acc[4 + mi][ni] = __builtin_amdgcn_mfma_f32_16x16x32_bf16(a[mi][1], bf[ni][1], acc[4 + mi][ni], 0, 0, 0);
            }
        __builtin_amdgcn_s_setprio(0);
        WV(2);
        BAR();
    }

    float bv[4];
    if (bias) {
        #pragma unroll
        for (int ni = 0; ni < 4; ++ni) bv[ni] = bias[bn + wn * 64 + ni * 16 + lr];
    }
    #pragma unroll
    for (int mi = 0; mi < 8; ++mi) {
        #pragma unroll
        for (int ni = 0; ni < 4; ++ni) {
            #pragma unroll
            for (int r = 0; r < 4; ++r) {
                const int row = bm + wm * 128 + mi * 16 + lk * 4 + r;
                const int col = bn + wn * 64 + ni * 16 + lr;
                float v = acc[mi][ni][r];
                if (bias) v += bv[ni];
                if constexpr (ACT == 2) { if (col >= 128) v = softplus_f(v); }
                if constexpr (sizeof(TC) == 4) C[(size_t)row * ldc + col] = v;
                else                           C[(size_t)row * ldc + col] = f2bf(v);
            }
        }
    }
}

// ---------------- depthwise causal conv (k=4) + bias + SiLU, 8 ch/thread ---------------
__global__ __launch_bounds__(256) void conv_silu_kernel(
    const u16* __restrict__ xz, const float* __restrict__ cw,
    const float* __restrict__ cb, u16* __restrict__ xc)
{
    const int idx8 = blockIdx.x * 256 + threadIdx.x;
    const int db  = (idx8 & 255) << 3;
    const int row = idx8 >> 8;
    const int l   = row & (L_SEQ - 1);

    float v[4][8];
    #pragma unroll
    for (int k = 0; k < 4; ++k) {
        const int ll = l - 3 + k;
        if (ll >= 0) {
            uint4 u = *reinterpret_cast<const uint4*>(xz + (size_t)(row - 3 + k) * 4096 + db);
            v[k][0]=bf2f((u16)(u.x&0xffff)); v[k][1]=bf2f((u16)(u.x>>16));
            v[k][2]=bf2f((u16)(u.y&0xffff)); v[k][3]=bf2f((u16)(u.y>>16));
            v[k][4]=bf2f((u16)(u.z&0xffff)); v[k][5]=bf2f((u16)(u.z>>16));
            v[k][6]=bf2f((u16)(u.w&0xffff)); v[k][7]=bf2f((u16)(u.w>>16));
        } else {
            #pragma unroll
            for (int j = 0; j < 8; ++j) v[k][j] = 0.f;
        }
    }
    float acc[8];
    {
        float4 c0 = *reinterpret_cast<const float4*>(cb + db);
        float4 c1 = *reinterpret_cast<const float4*>(cb + db + 4);
        acc[0]=c0.x; acc[1]=c0.y; acc[2]=c0.z; acc[3]=c0.w;
        acc[4]=c1.x; acc[5]=c1.y; acc[6]=c1.z; acc[7]=c1.w;
    }
    #pragma unroll
    for (int j = 0; j < 8; ++j) {
        const float4 wv = reinterpret_cast<const float4*>(cw)[db + j];
        acc[j] = fmaf(v[0][j], wv.x, acc[j]);
        acc[j] = fmaf(v[1][j], wv.y, acc[j]);
        acc[j] = fmaf(v[2][j], wv.z, acc[j]);
        acc[j] = fmaf(v[3][j], wv.w, acc[j]);
    }
    uint4 o;
    o.x = pack2(silu_f(acc[0]), silu_f(acc[1]));
    o.y = pack2(silu_f(acc[2]), silu_f(acc[3]));
    o.z = pack2(silu_f(acc[4]), silu_f(acc[5]));
    o.w = pack2(silu_f(acc[6]), silu_f(acc[7]));
    *reinterpret_cast<uint4*>(xc + (size_t)row * 2048 + db) = o;
}

// ============ selective scan ============
// dbc rows: [B(0..63) | C(64..127) | softplus(dt)(128..2175) | pad], stride DBCS=2304.
// Fast path: A[d][s] = A0[d]*(s+1) -> exp(A[s]*dt) = q^(s+1), q=exp(A0*dts).
// SPLIT=4: 256 thr = 64 d x 4 qtr, h2[8]/thread, e2=exp(ad*(base+1)) start power.
// (r11's spill came from __launch_bounds__(512,8), not the split — default bounds here.)

#define UNPACK8(dstp, u)  do {                                             \
    float4 _a, _b;                                                         \
    _a.x=bf2f((u16)((u).x&0xffff)); _a.y=bf2f((u16)((u).x>>16));           \
    _a.z=bf2f((u16)((u).y&0xffff)); _a.w=bf2f((u16)((u).y>>16));           \
    _b.x=bf2f((u16)((u).z&0xffff)); _b.y=bf2f((u16)((u).z>>16));           \
    _b.z=bf2f((u16)((u).w&0xffff)); _b.w=bf2f((u16)((u).w>>16));           \
    *reinterpret_cast<float4*>(dstp) = _a;                                 \
    *reinterpret_cast<float4*>((dstp) + 4) = _b;                           \
} while (0)

// ---------------- scan phase 1 (SPLIT=4, 256 thr) --------------------------------------
__global__ __launch_bounds__(256) void scan_phase1(
    const u16* __restrict__ xc,
    const u16* __restrict__ dbc,
    const float* __restrict__ A_log,
    const float* __restrict__ A0f, const unsigned char* __restrict__ okf,
    float* __restrict__ hend, float* __restrict__ sumdt,
    int nchunk, int chunk)
{
    const int tid  = threadIdx.x;
    const int dl   = tid >> 2, qtr = tid & 3;
    const int base = qtr * 16;
    const float kof = (float)(base + 1);
    const int d0   = blockIdx.x * DPBS;
    const int d    = d0 + dl;
    const int c = blockIdx.y, b = blockIdx.z;
    const int t0 = c * chunk;
    const size_t bL = (size_t)b * L_SEQ;

    __shared__ float dts_s[16][68];
    __shared__ float xcs_s[16][68];
    __shared__ float Bs_s[16][68];

    const float A0 = A0f[d];
    int fast = __syncthreads_and((int)okf[d]);

    f32x2 h2[8];
    #pragma unroll
    for (int j = 0; j < 8; ++j) h2[j] = (f32x2){0.f, 0.f};
    float sd = 0.f;

    const int ts8 = tid & 127;
    const int rr = ts8 >> 3, cc = (ts8 & 7) * 8;

    for (int ts = 0; ts < chunk; ts += 16) {
        __syncthreads();
        {
            const size_t row = bL + t0 + ts + rr;
            if (tid < 128) {
                uint4 v = *reinterpret_cast<const uint4*>(dbc + row * DBCS + 128 + d0 + cc);
                UNPACK8(&dts_s[rr][cc], v);
                uint4 u = *reinterpret_cast<const uint4*>(xc + row * 2048 + d0 + cc);
                UNPACK8(&xcs_s[rr][cc], u);
            } else {
                uint4 v = *reinterpret_cast<const uint4*>(dbc + row * DBCS + cc);
                UNPACK8(&Bs_s[rr][cc], v);
            }
        }
        __syncthreads();
        if (fast) {
            for (int r = 0; r < 16; ++r) {
                const float dts = dts_s[r][dl];
                const float xv  = xcs_s[r][dl];
                const float dtx = dts * xv;
                sd += dts;
                const float ad = A0 * dts;
                const float q  = __expf(ad);
                const float e2 = __expf(ad * kof);
                const float q2 = q * q, q4 = q2 * q2;
                f32x2 pA = {e2, e2 * q};
                f32x2 pB = {e2 * q2, e2 * q2 * q};
                const f32x2 q44 = {q4, q4};
                const f32x2 dtx2 = {dtx, dtx};
                #pragma unroll
                for (int g = 0; g < 4; ++g) {
                    const f32x4 Bq = *reinterpret_cast<const f32x4*>(&Bs_s[r][base + g * 4]);
                    const f32x2 B01 = {Bq[0], Bq[1]};
                    const f32x2 B23 = {Bq[2], Bq[3]};
                    h2[2*g]   = pA * h2[2*g]   + B01 * dtx2;
                    h2[2*g+1] = pB * h2[2*g+1] + B23 * dtx2;
                    pA = pA * q44; pB = pB * q44;
                }
            }
        } else {
            float* hs = (float*)h2;
            for (int r = 0; r < 16; ++r) {
                const float dts = dts_s[r][dl];
                const float xv  = xcs_s[r][dl];
                const float dtx = dts * xv;
                sd += dts;
                #pragma unroll
                for (int j = 0; j < 16; ++j) {
                    const float a = __expf(-__expf(A_log[d * DSTATE + base + j]) * dts);
                    hs[j] = fmaf(a, hs[j], dtx * Bs_s[r][base + j]);
                }
            }
        }
    }
    const size_t cb64 = ((size_t)b * nchunk + c) * DSTATE;
    const float* hs = (const float*)h2;
    #pragma unroll
    for (int j = 0; j < 16; ++j) hend[(cb64 + base + j) * DINNER + d] = hs[j];
    if (qtr == 0) sumdt[((size_t)b * nchunk + c) * DINNER + d] = sd;
}

// ---------------- scan phase 2 ---------------------------------------------------------
__global__ __launch_bounds__(256) void scan_phase2(
    float* __restrict__ hbuf, const float* __restrict__ sumdt,
    const float* __restrict__ A_log, int nchunk)
{
    const int idx = blockIdx.x * 256 + threadIdx.x;
    const int d = idx & (DINNER - 1);
    const int s = (idx >> 11) & (DSTATE - 1);
    const int b = idx >> 17;

    const float A = -__expf(A_log[d * DSTATE + s]);
    float h = 0.f;
    for (int c = 0; c < nchunk; ++c) {
        const size_t off = (((size_t)b * nchunk + c) * DSTATE + s) * DINNER + d;
        const float he = hbuf[off];
        const float ap = __expf(A * sumdt[((size_t)b * nchunk + c) * DINNER + d]);
        hbuf[off] = h;
        h = fmaf(ap, h, he);
    }
}

// ---------------- scan phase 3 (SPLIT=4, 256 thr) --------------------------------------
__global__ __launch_bounds__(256) void scan_phase3(
    u16* __restrict__ xc,
    const u16* __restrict__ dbc,
    const float* __restrict__ A_log,
    const float* __restrict__ A0f, const unsigned char* __restrict__ okf,
    const float* __restrict__ hinit,
    const float* __restrict__ D_param,
    int nchunk, int chunk)
{
    const int tid  = threadIdx.x;
    const int dl   = tid >> 2, qtr = tid & 3;
    const int base = qtr * 16;
    const float kof = (float)(base + 1);
    const int d0   = blockIdx.x * DPBS;
    const int d    = d0 + dl;
    const int c = blockIdx.y, b = blockIdx.z;
    const int t0 = c * chunk;
    const size_t bL = (size_t)b * L_SEQ;

    __shared__ float dts_s[16][68];
    __shared__ float xcs_s[16][68];
    __shared__ float BCs[16][132];

    const float A0 = A0f[d];
    int fast = __syncthreads_and((int)okf[d]);

    f32x2 h2[8];
    {
        const size_t cb64 = ((size_t)b * nchunk + c) * DSTATE;
        float* hs = (float*)h2;
        #pragma unroll
        for (int j = 0; j < 16; ++j) hs[j] = hinit[(cb64 + base + j) * DINNER + d];
    }
    const float Dp = D_param[d];

    const int ts8 = tid & 127;
    const int rrA = ts8 >> 3, ccA = (ts8 & 7) * 8;    // dts/xcs staging (threads 0-127)
    const int rrB = ts8 >> 3, ccB = (ts8 & 7) * 16;   // BCs staging (threads 128-255)

    for (int ts = 0; ts < chunk; ts += 16) {
        __syncthreads();
        {
            if (tid < 128) {
                const size_t row = bL + t0 + ts + rrA;
                uint4 v = *reinterpret_cast<const uint4*>(dbc + row * DBCS + 128 + d0 + ccA);
                UNPACK8(&dts_s[rrA][ccA], v);
                uint4 u = *reinterpret_cast<const uint4*>(xc + row * 2048 + d0 + ccA);
                UNPACK8(&xcs_s[rrA][ccA], u);
            } else {
                const size_t row = bL + t0 + ts + rrB;
                uint4 w0 = *reinterpret_cast<const uint4*>(dbc + row * DBCS + ccB);
                UNPACK8(&BCs[rrB][ccB], w0);
                uint4 w1 = *reinterpret_cast<const uint4*>(dbc + row * DBCS + ccB + 8);
                UNPACK8(&BCs[rrB][ccB + 8], w1);
            }
        }
        __syncthreads();
        if (fast) {
            for (int r = 0; r < 16; ++r) {
                const float dts = dts_s[r][dl];
                const float xv  = xcs_s[r][dl];
                const float dtx = dts * xv;
                const float ad = A0 * dts;
                const float q  = __expf(ad);
                const float e2 = __expf(ad * kof);
                const float q2 = q * q, q4 = q2 * q2;
                f32x2 pA = {e2, e2 * q};
                f32x2 pB = {e2 * q2, e2 * q2 * q};
                const f32x2 q44 = {q4, q4};
                const f32x2 dtx2 = {dtx, dtx};
                f32x2 y2 = {0.f, 0.f};
                #pragma unroll
                for (int g = 0; g < 4; ++g) {
                    const f32x4 Bq = *reinterpret_cast<const f32x4*>(&BCs[r][base + g * 4]);
                    const f32x4 Cq = *reinterpret_cast<const f32x4*>(&BCs[r][64 + base + g * 4]);
                    const f32x2 B01 = {Bq[0], Bq[1]};
                    const f32x2 B23 = {Bq[2], Bq[3]};
                    const f32x2 C01 = {Cq[0], Cq[1]};
                    const f32x2 C23 = {Cq[2], Cq[3]};
                    h2[2*g]   = pA * h2[2*g]   + B01 * dtx2;
                    h2[2*g+1] = pB * h2[2*g+1] + B23 * dtx2;
                    y2 = h2[2*g] * C01 + y2;
                    y2 = h2[2*g+1] * C23 + y2;
                    pA = pA * q44; pB = pB * q44;
                }
                float y = y2.x + y2.y;
                y += __shfl_xor(y, 1, 64);
                y += __shfl_xor(y, 2, 64);
                if (qtr == 0) {
                    const size_t row = bL + t0 + ts + r;
                    xc[row * 2048 + d] = f2bf(fmaf(xv, Dp, y));
                }
            }
        } else {
            float* hs = (float*)h2;
            for (int r = 0; r < 16; ++r) {
                const float dts = dts_s[r][dl];
                const float xv  = xcs_s[r][dl];
                const float dtx = dts * xv;
                float y = 0.f;
                #pragma unroll
                for (int j = 0; j < 16; ++j) {
                    const float a = __expf(-__expf(A_log[d * DSTATE + base + j]) * dts);
                    hs[j] = fmaf(a, hs[j], dtx * BCs[r][base + j]);
                    y = fmaf(hs[j], BCs[r][64 + base + j], y);
                }
                y += __shfl_xor(y, 1, 64);
                y += __shfl_xor(y, 2, 64);
                if (qtr == 0) {
                    const size_t row = bL + t0 + ts + r;
                    xc[row * 2048 + d] = f2bf(fmaf(xv, Dp, y));
                }
            }
        }
    }
}

// ---------------- RMSNorm * norm_w * silu(z), in-place on y ----------------------------
__global__ __launch_bounds__(256) void rms_gate_kernel(
    u16* __restrict__ y, const u16* __restrict__ xz,
    const float* __restrict__ norm_w)
{
    const int row = blockIdx.x;
    const int tid = threadIdx.x;
    const size_t ybase = (size_t)row * DINNER;
    const size_t zbase = (size_t)row * 4096 + DINNER;
    const int i8 = tid * 8;

    float yv[8];
    {
        uint4 u = *reinterpret_cast<const uint4*>(y + ybase + i8);
        yv[0]=bf2f((u16)(u.x&0xffff)); yv[1]=bf2f((u16)(u.x>>16));
        yv[2]=bf2f((u16)(u.y&0xffff)); yv[3]=bf2f((u16)(u.y>>16));
        yv[4]=bf2f((u16)(u.z&0xffff)); yv[5]=bf2f((u16)(u.z>>16));
        yv[6]=bf2f((u16)(u.w&0xffff)); yv[7]=bf2f((u16)(u.w>>16));
    }
    float ss = 0.f;
    #pragma unroll
    for (int j = 0; j < 8; ++j) ss = fmaf(yv[j], yv[j], ss);
    #pragma unroll
    for (int off = 32; off > 0; off >>= 1) ss += __shfl_down(ss, off, 64);
    __shared__ float sred[4];
    const int lane = tid & 63, wid = tid >> 6;
    if (lane == 0) sred[wid] = ss;
    __syncthreads();
    const float tot = sred[0] + sred[1] + sred[2] + sred[3];
    const float scale = rsqrtf(tot * (1.f / (float)DINNER) + 1.1920929e-07f);

    float zv[8];
    {
        uint4 u = *reinterpret_cast<const uint4*>(xz + zbase + i8);
        zv[0]=bf2f((u16)(u.x&0xffff)); zv[1]=bf2f((u16)(u.x>>16));
        zv[2]=bf2f((u16)(u.y&0xffff)); zv[3]=bf2f((u16)(u.y>>16));
        zv[4]=bf2f((u16)(u.z&0xffff)); zv[5]=bf2f((u16)(u.z>>16));
        zv[6]=bf2f((u16)(u.w&0xffff)); zv[7]=bf2f((u16)(u.w>>16));
    }
    float4 n0 = *reinterpret_cast<const float4*>(norm_w + i8);
    float4 n1 = *reinterpret_cast<const float4*>(norm_w + i8 + 4);
    const float nw[8] = {n0.x,n0.y,n0.z,n0.w,n1.x,n1.y,n1.z,n1.w};
    float o[8];
    #pragma unroll
    for (int j = 0; j < 8; ++j) o[j] = yv[j] * scale * nw[j] * silu_f(zv[j]);
    uint4 ov;
    ov.x = pack2(o[0], o[1]); ov.y = pack2(o[2], o[3]);
    ov.z = pack2(o[4], o[5]); ov.w = pack2(o[6], o[7]);
    *reinterpret_cast<uint4*>(y + ybase + i8) = ov;
}

extern "C" void kernel_launch(void* const* d_in, const int* in_sizes, int n_in,
                              void* d_out, int out_size, void* d_ws, size_t ws_size,
                              hipStream_t stream)
{
    const float* x       = (const float*)d_in[0];
    const float* W_in    = (const float*)d_in[1];
    const float* conv_w  = (const float*)d_in[2];
    const float* conv_b  = (const float*)d_in[3];
    const float* W_x     = (const float*)d_in[4];
    const float* W_dt    = (const float*)d_in[5];
    const float* b_dt    = (const float*)d_in[6];
    const float* A_log   = (const float*)d_in[7];
    const float* D_param = (const float*)d_in[8];
    const float* W_out   = (const float*)d_in[9];
    const float* norm_w  = (const float*)d_in[10];
    float* out = (float*)d_out;

    hipFuncSetAttribute(reinterpret_cast<const void*>(&gemm256<u16, 0>),
                        hipFuncAttributeMaxDynamicSharedMemorySize, 131072);
    hipFuncSetAttribute(reinterpret_cast<const void*>(&gemm256<u16, 2>),
                        hipFuncAttributeMaxDynamicSharedMemorySize, 131072);
    hipFuncSetAttribute(reinterpret_cast<const void*>(&gemm256<float, 0>),
                        hipFuncAttributeMaxDynamicSharedMemorySize, 131072);

    // ---- workspace layout (bytes) ----
    char* ws = (char*)d_ws;
    u16* xz  = (u16*)(ws);                   // 8192 x 4096 bf16 (x_ssm | z)
    u16* xc  = (u16*)(ws + 67108864ull);     // 8192 x 2048 bf16 (x_conv, then y)
    u16* dbc = (u16*)(ws + 100663296ull);    // 8192 x 2304 bf16 [B | C | sp(dt) | pad]
    u16* xbf  = dbc;                         // x bf16 scratch (dead before dbc written)
    u16* Wxbf = xz;                          // W_x bf16 scratch (dead before xz written)
    u16* Wt_out = (u16*)(ws + 138412032ull); // 1024 x 2048 bf16
    float* bias2304 = (float*)(ws + 142606336ull);      // 2304 fp32
    float* A0f = (float*)(ws + 142615552ull);           // 2048 fp32
    unsigned char* okf = (unsigned char*)(ws + 142623744ull); // 2048 u8
    const size_t fixed_bytes = 142625792ull;
    const size_t per_chunk = 2ull * DSTATE * DINNER * 4 + 2ull * DINNER * 4; // 1,064,960
    int nchunk = 32;
    while (nchunk > 1 && fixed_bytes + (size_t)nchunk * per_chunk > ws_size) nchunk >>= 1;
    const int chunk = L_SEQ / nchunk;
    float* hbuf = (float*)(ws + fixed_bytes);
    float* sdt  = (float*)(ws + fixed_bytes + (size_t)nchunk * 2ull * DSTATE * DINNER * 4);

    u16* Wt_in = (u16*)d_out;                // 4096 x 1024 (d_out scratch, dead by final GEMM)
    u16* Wt_x  = Wt_in + 4194304ull;         // 2304 x 2048: [B|C]^T rows 0..127, WcombT 128..2175, pad
    u16* Wt_dt = Wt_x + 4718592ull;          // 2048 x 2048

    const int M = NROWS; // 8192

    // 0) converts / transposes / bias / A0 precompute / pad-zero
    f32_to_bf16_kernel<<<(M * DMODEL) / 1024, 256, 0, stream>>>(x, xbf);
    f32_to_bf16_kernel<<<(DINNER * 2176) / 1024, 256, 0, stream>>>(W_x, Wxbf);
    transpose_bf16_kernel<<<dim3(4096 / 32, 1024 / 32), 256, 0, stream>>>(W_in, Wt_in, 1024, 4096);
    transpose_bf16_kernel<<<dim3(4, 2048 / 32), 256, 0, stream>>>(W_x, Wt_x, 2048, 2176); // cols 0..127
    transpose_bf16_kernel<<<dim3(2048 / 32, 2048 / 32), 256, 0, stream>>>(W_dt, Wt_dt, 2048, 2048);
    transpose_bf16_kernel<<<dim3(1024 / 32, 2048 / 32), 256, 0, stream>>>(W_out, Wt_out, 2048, 1024);
    bias_cat_kernel<<<9, 256, 0, stream>>>(b_dt, bias2304);
    a0_kernel<<<DINNER / 256, 256, 0, stream>>>(A_log, A0f, okf);
    hipMemsetAsync(Wt_x + 2176ull * 2048, 0, 128ull * 2048 * 2, stream);  // pad rows
    // 0b) WcombT = W_dt^T @ W_x[:,128:]^T -> Wt_x rows 128..2175   [128^2: 256 wgs = 1/CU]
    mfma_gemm<u16><<<dim3(2048 / 128, 2048 / 128), 256, 0, stream>>>(
        Wt_dt, 2048, Wxbf + 128, 2176, Wt_x + 128ull * 2048, 2048, 2048, nullptr);

    // 1) xz = x @ W_in                                  [256^2 8-phase]
    gemm256<u16, 0><<<dim3(4096 / 256, M / 256), 512, 131072, stream>>>(
        xbf, DMODEL, Wt_in, DMODEL, xz, 4096, DMODEL, nullptr);
    // 2) xc = silu(causal_dwconv(x_ssm) + conv_b)
    conv_silu_kernel<<<(M * DINNER) / (256 * 8), 256, 0, stream>>>(xz, conv_w, conv_b, xc);
    // 3) dbc = xc @ [W_x[:,:128] | Wcomb | pad] + bias; softplus on cols>=128  [256^2]
    gemm256<u16, 2><<<dim3(DBCS / 256, M / 256), 512, 131072, stream>>>(
        xc, DINNER, Wt_x, DINNER, dbc, DBCS, DINNER, bias2304);
    // 4-6) chunked selective scan
    scan_phase1<<<dim3(DINNER / DPBS, nchunk, NB), 256, 0, stream>>>(
        xc, dbc, A_log, A0f, okf, hbuf, sdt, nchunk, chunk);
    scan_phase2<<<(NB * DINNER * DSTATE) / 256, 256, 0, stream>>>(hbuf, sdt, A_log, nchunk);
    scan_phase3<<<dim3(DINNER / DPBS, nchunk, NB), 256, 0, stream>>>(
        xc, dbc, A_log, A0f, okf, hbuf, D_param, nchunk, chunk);
    // 7) y = rmsnorm(y) * norm_w * silu(z)
    rms_gate_kernel<<<M, 256, 0, stream>>>(xc, xz, norm_w);
    // 8) out = y @ W_out                                [256^2 8-phase, fp32 out]
    gemm256<float, 0><<<dim3(1024 / 256, M / 256), 512, 131072, stream>>>(
        xc, DINNER, Wt_out, DINNER, out, DMODEL, DINNER, nullptr);
}

// Round 14
// 625.789 us; speedup vs baseline: 1.0277x; 1.0277x over previous
//
#include <hip/hip_runtime.h>
#include <hip/hip_bf16.h>

#define L_SEQ   4096
#define DMODEL  1024
#define DINNER  2048
#define DSTATE  64
#define NB      2
#define DPB     128          // d-channels per scan block (SPLIT=2)
#define DBCS    2304         // dbc row stride (B|C|dt|pad)
#define NROWS   (NB * L_SEQ) // 8192

typedef unsigned short u16;
typedef __attribute__((ext_vector_type(8))) short bf16x8;
typedef __attribute__((ext_vector_type(4))) float f32x4;
typedef __attribute__((ext_vector_type(2))) float f32x2;

__device__ __forceinline__ float silu_f(float x)  { return x / (1.f + __expf(-x)); }
__device__ __forceinline__ float softplus_f(float x) {
    return x > 15.f ? x : __logf(1.f + __expf(x));
}
__device__ __forceinline__ float bf2f(u16 u) { return __uint_as_float(((unsigned)u) << 16); }
__device__ __forceinline__ u16 f2bf(float f) {
    __hip_bfloat16 h = __float2bfloat16(f);
    return *reinterpret_cast<u16*>(&h);
}
__device__ __forceinline__ unsigned pack2(float a, float b) {
    return (unsigned)f2bf(a) | ((unsigned)f2bf(b) << 16);
}

// ---------------- fp32 -> bf16 elementwise convert -------------------------------------
__global__ __launch_bounds__(256) void f32_to_bf16_kernel(
    const float* __restrict__ in, u16* __restrict__ out)
{
    const int i = (blockIdx.x * 256 + threadIdx.x) * 4;
    float4 v = *reinterpret_cast<const float4*>(in + i);
    ushort4 o;
    o.x = f2bf(v.x); o.y = f2bf(v.y); o.z = f2bf(v.z); o.w = f2bf(v.w);
    *reinterpret_cast<ushort4*>(out + i) = o;
}

// ---------------- W[K][N] fp32 -> Wt[N][K] bf16 (tiled transpose) ----------------------
__global__ __launch_bounds__(256) void transpose_bf16_kernel(
    const float* __restrict__ W, u16* __restrict__ Wt, int K, int N)
{
    __shared__ float t[32][33];
    const int n0 = blockIdx.x * 32, k0 = blockIdx.y * 32;
    const int tx = threadIdx.x & 31, ty = threadIdx.x >> 5;   // ty 0..7
    #pragma unroll
    for (int i = 0; i < 32; i += 8)
        t[ty + i][tx] = W[(size_t)(k0 + ty + i) * N + n0 + tx];
    __syncthreads();
    #pragma unroll
    for (int i = 0; i < 32; i += 8)
        Wt[(size_t)(n0 + ty + i) * K + k0 + tx] = f2bf(t[tx][ty + i]);
}

// ---------------- build [0_128 | b_dt | 0_pad] bias vector -----------------------------
__global__ __launch_bounds__(256) void bias_cat_kernel(
    const float* __restrict__ b_dt, float* __restrict__ bias)
{
    const int i = blockIdx.x * 256 + threadIdx.x;   // 0..2303
    float v = 0.f;
    if (i >= 128 && i < 128 + DINNER) v = b_dt[i - 128];
    bias[i] = v;
}

// ---------------- A-structure precompute: A0[d], ok[d] ---------------------------------
__global__ __launch_bounds__(256) void a0_kernel(
    const float* __restrict__ A_log, float* __restrict__ A0f,
    unsigned char* __restrict__ okf)
{
    const int d = blockIdx.x * 256 + threadIdx.x;   // 2048 threads
    const float A0 = -__expf(A_log[d * DSTATE]);
    int ok = 1;
    for (int s = 1; s < DSTATE; ++s) {
        const float As = -__expf(A_log[d * DSTATE + s]);
        ok &= (fabsf(As - A0 * (float)(s + 1)) <= 1e-3f * (float)(s + 1));
    }
    A0f[d] = A0;
    okf[d] = (unsigned char)ok;
}

// ---------------- 128x128 bf16 MFMA GEMM (m97 structure + XCD swizzle) -----------------
template <typename TC>
__global__ __launch_bounds__(256) void mfma_gemm(
    const u16* __restrict__ A, int lda,      // [M][K] bf16
    const u16* __restrict__ Bt, int ldb,     // [N][K] bf16
    TC* __restrict__ C, int ldc,
    int K, const float* __restrict__ bias)
{
    __shared__ u16 As[128 * 32];
    __shared__ u16 Bs[128 * 32];
    const int tid  = threadIdx.x;
    const int lane = tid & 63;
    const int w    = tid >> 6;
    const int wm   = w >> 1, wn = w & 1;

    const int gx = gridDim.x;
    const int nwg = gx * gridDim.y;
    int wg = blockIdx.y * gx + blockIdx.x;
    if ((nwg & 7) == 0) wg = (wg & 7) * (nwg >> 3) + (wg >> 3);
    const int bm = (wg / gx) * 128, bn = (wg % gx) * 128;

    const int lr = lane & 15, lk = lane >> 4;
    const int srow  = lane >> 2;
    const int scolb = (lane & 3) * 16;
    const size_t ldaB = (size_t)lda * 2, ldbB = (size_t)ldb * 2;

    const char* Ab = (const char*)A + (size_t)bm * ldaB;
    const char* Bb = (const char*)Bt + (size_t)bn * ldbB;
    char* AsB = (char*)As;
    char* BsB = (char*)Bs;

    f32x4 acc[4][4] = {};

    for (int k0 = 0; k0 < K; k0 += 32) {
        const size_t kb = (size_t)k0 * 2;
        #pragma unroll
        for (int i = 0; i < 2; ++i) {
            const int row = i * 64 + w * 16 + srow;
            __builtin_amdgcn_global_load_lds(
                (const __attribute__((address_space(1))) void*)(Ab + (size_t)row * ldaB + kb + scolb),
                (__attribute__((address_space(3))) void*)(AsB + i * 4096 + w * 1024),
                16, 0, 0);
            __builtin_amdgcn_global_load_lds(
                (const __attribute__((address_space(1))) void*)(Bb + (size_t)row * ldbB + kb + scolb),
                (__attribute__((address_space(3))) void*)(BsB + i * 4096 + w * 1024),
                16, 0, 0);
        }
        __syncthreads();
        bf16x8 a[4], b[4];
        #pragma unroll
        for (int mi = 0; mi < 4; ++mi)
            a[mi] = *reinterpret_cast<const bf16x8*>(&As[(wm * 64 + mi * 16 + lr) * 32 + lk * 8]);
        #pragma unroll
        for (int ni = 0; ni < 4; ++ni)
            b[ni] = *reinterpret_cast<const bf16x8*>(&Bs[(wn * 64 + ni * 16 + lr) * 32 + lk * 8]);
        #pragma unroll
        for (int mi = 0; mi < 4; ++mi)
            #pragma unroll
            for (int ni = 0; ni < 4; ++ni)
                acc[mi][ni] = __builtin_amdgcn_mfma_f32_16x16x32_bf16(a[mi], b[ni], acc[mi][ni], 0, 0, 0);
        __syncthreads();
    }

    float bv[4];
    if (bias) {
        #pragma unroll
        for (int ni = 0; ni < 4; ++ni) bv[ni] = bias[bn + wn * 64 + ni * 16 + lr];
    }
    #pragma unroll
    for (int mi = 0; mi < 4; ++mi) {
        #pragma unroll
        for (int ni = 0; ni < 4; ++ni) {
            #pragma unroll
            for (int r = 0; r < 4; ++r) {
                const int row = bm + wm * 64 + mi * 16 + lk * 4 + r;
                const int col = bn + wn * 64 + ni * 16 + lr;
                float v = acc[mi][ni][r];
                if (bias) v += bv[ni];
                if constexpr (sizeof(TC) == 4) C[(size_t)row * ldc + col] = v;
                else                           C[(size_t)row * ldc + col] = f2bf(v);
            }
        }
    }
}

// ---------------- 256x256 BK=64 8-phase bf16 MFMA GEMM (T2+T3+T4+T5) -------------------
// ACT: 0 = none, 2 = softplus on cols >= 128 (fused dt activation).
#define BAR()  asm volatile("s_barrier" ::: "memory")
#define WV(n)  asm volatile("s_waitcnt vmcnt(" #n ")" ::: "memory")
#define STG16(s, d) __builtin_amdgcn_global_load_lds( \
    (const __attribute__((address_space(1))) void*)(s), \
    (__attribute__((address_space(3))) void*)(d), 16, 0, 0)

template <typename TC, int ACT>
__global__ __launch_bounds__(512, 2) void gemm256(
    const u16* __restrict__ A, int lda,      // [M][K] bf16
    const u16* __restrict__ Bt, int ldb,     // [N][K] bf16
    TC* __restrict__ C, int ldc,
    int K, const float* __restrict__ bias)
{
    extern __shared__ char lds[];            // 131072 B
    const int tid = threadIdx.x;
    const int l = tid & 63, w = tid >> 6;
    const int wm = w >> 2, wn = w & 3;
    const int lr = l & 15, lk = l >> 4;

    const int gx = gridDim.x;
    const int nwg = gx * gridDim.y;
    int wg = blockIdx.y * gx + blockIdx.x;
    wg = (wg & 7) * (nwg >> 3) + (wg >> 3);  // all grids %8==0
    const int bm = (wg / gx) * 256, bn = (wg % gx) * 256;

    const size_t ldaB = (size_t)lda * 2, ldbB = (size_t)ldb * 2;
    const int gsw = (((l & 7) ^ (l >> 3)) << 4);
    const char* aSrc = (const char*)A + (size_t)(bm + w * 8 + (l >> 3)) * ldaB + gsw;
    const char* bSrc = (const char*)Bt + (size_t)(bn + w * 8 + (l >> 3)) * ldbB + gsw;
    const int csw0 = (lk * 16) ^ ((lr & 7) << 4);
    const int wdst = w * 1024;

    const int nk = K >> 6;
    f32x4 acc[8][4] = {};

    {
        STG16(aSrc + (size_t)(0 * 64) * ldaB, lds + 0 * 8192 + wdst);
        STG16(aSrc + (size_t)(2 * 64) * ldaB, lds + 2 * 8192 + wdst);
        STG16(bSrc + (size_t)(0 * 64) * ldbB, lds + 32768 + 0 * 8192 + wdst);
        STG16(bSrc + (size_t)(1 * 64) * ldbB, lds + 32768 + 1 * 8192 + wdst);
        STG16(bSrc + (size_t)(2 * 64) * ldbB, lds + 32768 + 2 * 8192 + wdst);
        STG16(bSrc + (size_t)(3 * 64) * ldbB, lds + 32768 + 3 * 8192 + wdst);
        STG16(aSrc + (size_t)(1 * 64) * ldaB, lds + 1 * 8192 + wdst);
        STG16(aSrc + (size_t)(3 * 64) * ldaB, lds + 3 * 8192 + wdst);
        WV(2);
        BAR();
    }

    for (int t = 0; t < nk; ++t) {
        const int p = t & 1;
        const char* Ar = lds + (p << 16);
        const char* Br = Ar + 32768;
        const int tn = (t + 1 < nk) ? t + 1 : t;
        char* dq = lds + (((t + 1) & 1) << 16);
        const size_t Tb = (size_t)tn << 7;
        const char* aS = aSrc + Tb;
        const char* bS = bSrc + Tb;

        bf16x8 a[4][2], bf[2][2];

        // ---- PH0 ----
        #pragma unroll
        for (int mi = 0; mi < 4; ++mi) {
            const int ro = (wm * 128 + mi * 16 + lr) * 128;
            a[mi][0] = *reinterpret_cast<const bf16x8*>(Ar + ro + csw0);
            a[mi][1] = *reinterpret_cast<const bf16x8*>(Ar + ro + (csw0 ^ 64));
        }
        #pragma unroll
        for (int ni = 0; ni < 2; ++ni) {
            const int ro = (wn * 64 + ni * 16 + lr) * 128;
            bf[ni][0] = *reinterpret_cast<const bf16x8*>(Br + ro + csw0);
            bf[ni][1] = *reinterpret_cast<const bf16x8*>(Br + ro + (csw0 ^ 64));
        }
        STG16(aS + (size_t)(0 * 64) * ldaB, dq + 0 * 8192 + wdst);
        STG16(aS + (size_t)(2 * 64) * ldaB, dq + 2 * 8192 + wdst);
        BAR();
        __builtin_amdgcn_s_setprio(1);
        #pragma unroll
        for (int mi = 0; mi < 4; ++mi)
            #pragma unroll
            for (int ni = 0; ni < 2; ++ni) {
                acc[mi][ni] = __builtin_amdgcn_mfma_f32_16x16x32_bf16(a[mi][0], bf[ni][0], acc[mi][ni], 0, 0, 0);
                acc[mi][ni] = __builtin_amdgcn_mfma_f32_16x16x32_bf16(a[mi][1], bf[ni][1], acc[mi][ni], 0, 0, 0);
            }
        __builtin_amdgcn_s_setprio(0);
        BAR();

        // ---- PH1 ----
        #pragma unroll
        for (int ni = 0; ni < 2; ++ni) {
            const int ro = (wn * 64 + (2 + ni) * 16 + lr) * 128;
            bf[ni][0] = *reinterpret_cast<const bf16x8*>(Br + ro + csw0);
            bf[ni][1] = *reinterpret_cast<const bf16x8*>(Br + ro + (csw0 ^ 64));
        }
        STG16(bS + (size_t)(0 * 64) * ldbB, dq + 32768 + 0 * 8192 + wdst);
        STG16(bS + (size_t)(1 * 64) * ldbB, dq + 32768 + 1 * 8192 + wdst);
        BAR();
        __builtin_amdgcn_s_setprio(1);
        #pragma unroll
        for (int mi = 0; mi < 4; ++mi)
            #pragma unroll
            for (int ni = 0; ni < 2; ++ni) {
                acc[mi][2 + ni] = __builtin_amdgcn_mfma_f32_16x16x32_bf16(a[mi][0], bf[ni][0], acc[mi][2 + ni], 0, 0, 0);
                acc[mi][2 + ni] = __builtin_amdgcn_mfma_f32_16x16x32_bf16(a[mi][1], bf[ni][1], acc[mi][2 + ni], 0, 0, 0);
            }
        __builtin_amdgcn_s_setprio(0);
        WV(4);
        BAR();

        // ---- PH2 ----
        #pragma unroll
        for (int mi = 0; mi < 4; ++mi) {
            const int ro = (wm * 128 + (4 + mi) * 16 + lr) * 128;
            a[mi][0] = *reinterpret_cast<const bf16x8*>(Ar + ro + csw0);
            a[mi][1] = *reinterpret_cast<const bf16x8*>(Ar + ro + (csw0 ^ 64));
        }
        STG16(bS + (size_t)(2 * 64) * ldbB, dq + 32768 + 2 * 8192 + wdst);
        STG16(bS + (size_t)(3 * 64) * ldbB, dq + 32768 + 3 * 8192 + wdst);
        BAR();
        __builtin_amdgcn_s_setprio(1);
        #pragma unroll
        for (int mi = 0; mi < 4; ++mi)
            #pragma unroll
            for (int ni = 0; ni < 2; ++ni) {
                acc[4 + mi][2 + ni] = __builtin_amdgcn_mfma_f32_16x16x32_bf16(a[mi][0], bf[ni][0], acc[4 + mi][2 + ni], 0, 0, 0);
                acc[4 + mi][2 + ni] = __builtin_amdgcn_mfma_f32_16x16x32_bf16(a[mi][1], bf[ni][1], acc[4 + mi][2 + ni], 0, 0, 0);
            }
        __builtin_amdgcn_s_setprio(0);
        BAR();

        // ---- PH3 ----
        #pragma unroll
        for (int ni = 0; ni < 2; ++ni) {
            const int ro = (wn * 64 + ni * 16 + lr) * 128;
            bf[ni][0] = *reinterpret_cast<const bf16x8*>(Br + ro + csw0);
            bf[ni][1] = *reinterpret_cast<const bf16x8*>(Br + ro + (csw0 ^ 64));
        }
        STG16(aS + (size_t)(1 * 64) * ldaB, dq + 1 * 8192 + wdst);
        STG16(aS + (size_t)(3 * 64) * ldaB, dq + 3 * 8192 + wdst);
        BAR();
        __builtin_amdgcn_s_setprio(1);
        #pragma unroll
        for (int mi = 0; mi < 4; ++mi)
            #pragma unroll
            for (int ni = 0; ni < 2; ++ni) {
                acc[4 + mi][ni] = __builtin_amdgcn_mfma_f32_16x16x32_bf16(a[mi][0], bf[ni][0], acc[4 + mi][ni], 0, 0, 0);
                acc[4 + mi][ni] = __builtin_amdgcn_mfma_f32_16x16x32_bf16(a[mi][1], bf[ni][1], acc[4 + mi][ni], 0, 0, 0);
            }
        __builtin_amdgcn_s_setprio(0);
        WV(2);
        BAR();
    }

    float bv[4];
    if (bias) {
        #pragma unroll
        for (int ni = 0; ni < 4; ++ni) bv[ni] = bias[bn + wn * 64 + ni * 16 + lr];
    }
    #pragma unroll
    for (int mi = 0; mi < 8; ++mi) {
        #pragma unroll
        for (int ni = 0; ni < 4; ++ni) {
            #pragma unroll
            for (int r = 0; r < 4; ++r) {
                const int row = bm + wm * 128 + mi * 16 + lk * 4 + r;
                const int col = bn + wn * 64 + ni * 16 + lr;
                float v = acc[mi][ni][r];
                if (bias) v += bv[ni];
                if constexpr (ACT == 2) { if (col >= 128) v = softplus_f(v); }
                if constexpr (sizeof(TC) == 4) C[(size_t)row * ldc + col] = v;
                else                           C[(size_t)row * ldc + col] = f2bf(v);
            }
        }
    }
}

// ---------------- depthwise causal conv (k=4) + bias + SiLU, 8 ch/thread ---------------
__global__ __launch_bounds__(256) void conv_silu_kernel(
    const u16* __restrict__ xz, const float* __restrict__ cw,
    const float* __restrict__ cb, u16* __restrict__ xc)
{
    const int idx8 = blockIdx.x * 256 + threadIdx.x;
    const int db  = (idx8 & 255) << 3;
    const int row = idx8 >> 8;
    const int l   = row & (L_SEQ - 1);

    float v[4][8];
    #pragma unroll
    for (int k = 0; k < 4; ++k) {
        const int ll = l - 3 + k;
        if (ll >= 0) {
            uint4 u = *reinterpret_cast<const uint4*>(xz + (size_t)(row - 3 + k) * 4096 + db);
            v[k][0]=bf2f((u16)(u.x&0xffff)); v[k][1]=bf2f((u16)(u.x>>16));
            v[k][2]=bf2f((u16)(u.y&0xffff)); v[k][3]=bf2f((u16)(u.y>>16));
            v[k][4]=bf2f((u16)(u.z&0xffff)); v[k][5]=bf2f((u16)(u.z>>16));
            v[k][6]=bf2f((u16)(u.w&0xffff)); v[k][7]=bf2f((u16)(u.w>>16));
        } else {
            #pragma unroll
            for (int j = 0; j < 8; ++j) v[k][j] = 0.f;
        }
    }
    float acc[8];
    {
        float4 c0 = *reinterpret_cast<const float4*>(cb + db);
        float4 c1 = *reinterpret_cast<const float4*>(cb + db + 4);
        acc[0]=c0.x; acc[1]=c0.y; acc[2]=c0.z; acc[3]=c0.w;
        acc[4]=c1.x; acc[5]=c1.y; acc[6]=c1.z; acc[7]=c1.w;
    }
    #pragma unroll
    for (int j = 0; j < 8; ++j) {
        const float4 wv = reinterpret_cast<const float4*>(cw)[db + j];
        acc[j] = fmaf(v[0][j], wv.x, acc[j]);
        acc[j] = fmaf(v[1][j], wv.y, acc[j]);
        acc[j] = fmaf(v[2][j], wv.z, acc[j]);
        acc[j] = fmaf(v[3][j], wv.w, acc[j]);
    }
    uint4 o;
    o.x = pack2(silu_f(acc[0]), silu_f(acc[1]));
    o.y = pack2(silu_f(acc[2]), silu_f(acc[3]));
    o.z = pack2(silu_f(acc[4]), silu_f(acc[5]));
    o.w = pack2(silu_f(acc[6]), silu_f(acc[7]));
    *reinterpret_cast<uint4*>(xc + (size_t)row * 2048 + db) = o;
}

// ============ selective scan ============
// dbc rows: [B(0..63) | C(64..127) | softplus(dt)(128..2175) | pad], stride DBCS=2304.
// Fast path: A[d][s] = A0[d]*(s+1) -> exp(A[s]*dt) = q^(s+1), q=exp(A0*dts).
// A0/ok precomputed. f32x2 packed state. SPLIT=2 (r11 512-thr spilled; r13 SPLIT=4
// doubled exps + 4x bank conflicts — both regressed; this is the measured-best shape).

#define UNPACK8(dstp, u)  do {                                             \
    float4 _a, _b;                                                         \
    _a.x=bf2f((u16)((u).x&0xffff)); _a.y=bf2f((u16)((u).x>>16));           \
    _a.z=bf2f((u16)((u).y&0xffff)); _a.w=bf2f((u16)((u).y>>16));           \
    _b.x=bf2f((u16)((u).z&0xffff)); _b.y=bf2f((u16)((u).z>>16));           \
    _b.z=bf2f((u16)((u).w&0xffff)); _b.w=bf2f((u16)((u).w>>16));           \
    *reinterpret_cast<float4*>(dstp) = _a;                                 \
    *reinterpret_cast<float4*>((dstp) + 4) = _b;                           \
} while (0)

// ---------------- scan phase 1 (SPLIT=2, 256 thr) --------------------------------------
__global__ __launch_bounds__(256) void scan_phase1(
    const u16* __restrict__ xc,
    const u16* __restrict__ dbc,
    const float* __restrict__ A_log,
    const float* __restrict__ A0f, const unsigned char* __restrict__ okf,
    float* __restrict__ hend, float* __restrict__ sumdt,
    int nchunk, int chunk)
{
    const int tid  = threadIdx.x;
    const int dl   = tid >> 1, half = tid & 1;
    const int base = half * 32;
    const int d0   = blockIdx.x * DPB;
    const int d    = d0 + dl;
    const int c = blockIdx.y, b = blockIdx.z;
    const int t0 = c * chunk;
    const size_t bL = (size_t)b * L_SEQ;

    __shared__ float dts_s[16][132];
    __shared__ float xcs_s[16][132];
    __shared__ float Bs_s[16][68];

    const float A0 = A0f[d];
    int fast = __syncthreads_and((int)okf[d]);

    f32x2 h2[16];
    #pragma unroll
    for (int j = 0; j < 16; ++j) h2[j] = (f32x2){0.f, 0.f};
    float sd = 0.f;

    for (int ts = 0; ts < chunk; ts += 16) {
        __syncthreads();
        {
            const int rr = tid >> 4, cc = (tid & 15) * 8;
            const size_t row = bL + t0 + ts + rr;
            uint4 v = *reinterpret_cast<const uint4*>(dbc + row * DBCS + 128 + d0 + cc);
            UNPACK8(&dts_s[rr][cc], v);
            uint4 u = *reinterpret_cast<const uint4*>(xc + row * 2048 + d0 + cc);
            UNPACK8(&xcs_s[rr][cc], u);
        }
        if (tid < 128) {
            const int rb = tid >> 3, cb = (tid & 7) * 8;
            const size_t row = bL + t0 + ts + rb;
            uint4 v = *reinterpret_cast<const uint4*>(dbc + row * DBCS + cb);
            UNPACK8(&Bs_s[rb][cb], v);
        }
        __syncthreads();
        if (fast) {
            for (int r = 0; r < 16; ++r) {
                const float dts = dts_s[r][dl];
                const float xv  = xcs_s[r][dl];
                const float dtx = dts * xv;
                sd += dts;
                const float q  = __expf(A0 * dts);
                const float q2 = q * q, q3 = q2 * q, q4 = q2 * q2;
                const float q8 = q4 * q4, q16 = q8 * q8, q32 = q16 * q16;
                const float qb = half ? q32 : 1.f;
                f32x2 pA = {qb * q, qb * q2};
                f32x2 pB = {qb * q3, qb * q4};
                const f32x2 q44 = {q4, q4};
                const f32x2 dtx2 = {dtx, dtx};
                #pragma unroll
                for (int g = 0; g < 8; ++g) {
                    const f32x4 Bq = *reinterpret_cast<const f32x4*>(&Bs_s[r][base + g * 4]);
                    const f32x2 B01 = {Bq[0], Bq[1]};
                    const f32x2 B23 = {Bq[2], Bq[3]};
                    h2[2*g]   = pA * h2[2*g]   + B01 * dtx2;
                    h2[2*g+1] = pB * h2[2*g+1] + B23 * dtx2;
                    pA = pA * q44; pB = pB * q44;
                }
            }
        } else {
            float* hs = (float*)h2;
            for (int r = 0; r < 16; ++r) {
                const float dts = dts_s[r][dl];
                const float xv  = xcs_s[r][dl];
                const float dtx = dts * xv;
                sd += dts;
                #pragma unroll
                for (int j = 0; j < 32; ++j) {
                    const float a = __expf(-__expf(A_log[d * DSTATE + base + j]) * dts);
                    hs[j] = fmaf(a, hs[j], dtx * Bs_s[r][base + j]);
                }
            }
        }
    }
    const size_t cb64 = ((size_t)b * nchunk + c) * DSTATE;
    const float* hs = (const float*)h2;
    #pragma unroll
    for (int j = 0; j < 32; ++j) hend[(cb64 + base + j) * DINNER + d] = hs[j];
    if (half == 0) sumdt[((size_t)b * nchunk + c) * DINNER + d] = sd;
}

// ---------------- scan phase 2 ---------------------------------------------------------
__global__ __launch_bounds__(256) void scan_phase2(
    float* __restrict__ hbuf, const float* __restrict__ sumdt,
    const float* __restrict__ A_log, int nchunk)
{
    const int idx = blockIdx.x * 256 + threadIdx.x;
    const int d = idx & (DINNER - 1);
    const int s = (idx >> 11) & (DSTATE - 1);
    const int b = idx >> 17;

    const float A = -__expf(A_log[d * DSTATE + s]);
    float h = 0.f;
    for (int c = 0; c < nchunk; ++c) {
        const size_t off = (((size_t)b * nchunk + c) * DSTATE + s) * DINNER + d;
        const float he = hbuf[off];
        const float ap = __expf(A * sumdt[((size_t)b * nchunk + c) * DINNER + d]);
        hbuf[off] = h;
        h = fmaf(ap, h, he);
    }
}

// ---------------- scan phase 3 (SPLIT=2, 256 thr) --------------------------------------
__global__ __launch_bounds__(256) void scan_phase3(
    u16* __restrict__ xc,
    const u16* __restrict__ dbc,
    const float* __restrict__ A_log,
    const float* __restrict__ A0f, const unsigned char* __restrict__ okf,
    const float* __restrict__ hinit,
    const float* __restrict__ D_param,
    int nchunk, int chunk)
{
    const int tid  = threadIdx.x;
    const int dl   = tid >> 1, half = tid & 1;
    const int base = half * 32;
    const int d0   = blockIdx.x * DPB;
    const int d    = d0 + dl;
    const int c = blockIdx.y, b = blockIdx.z;
    const int t0 = c * chunk;
    const size_t bL = (size_t)b * L_SEQ;

    __shared__ float dts_s[16][132];
    __shared__ float xcs_s[16][132];
    __shared__ float BCs[16][132];

    const float A0 = A0f[d];
    int fast = __syncthreads_and((int)okf[d]);

    f32x2 h2[16];
    {
        const size_t cb64 = ((size_t)b * nchunk + c) * DSTATE;
        float* hs = (float*)h2;
        #pragma unroll
        for (int j = 0; j < 32; ++j) hs[j] = hinit[(cb64 + base + j) * DINNER + d];
    }
    const float Dp = D_param[d];

    for (int ts = 0; ts < chunk; ts += 16) {
        __syncthreads();
        {
            const int rr = tid >> 4, cc = (tid & 15) * 8;
            const size_t row = bL + t0 + ts + rr;
            uint4 v = *reinterpret_cast<const uint4*>(dbc + row * DBCS + 128 + d0 + cc);
            UNPACK8(&dts_s[rr][cc], v);
            uint4 u = *reinterpret_cast<const uint4*>(xc + row * 2048 + d0 + cc);
            UNPACK8(&xcs_s[rr][cc], u);
            uint4 w = *reinterpret_cast<const uint4*>(dbc + row * DBCS + cc);
            UNPACK8(&BCs[rr][cc], w);
        }
        __syncthreads();
        if (fast) {
            for (int r = 0; r < 16; ++r) {
                const float dts = dts_s[r][dl];
                const float xv  = xcs_s[r][dl];
                const float dtx = dts * xv;
                const float q  = __expf(A0 * dts);
                const float q2 = q * q, q3 = q2 * q, q4 = q2 * q2;
                const float q8 = q4 * q4, q16 = q8 * q8, q32 = q16 * q16;
                const float qb = half ? q32 : 1.f;
                f32x2 pA = {qb * q, qb * q2};
                f32x2 pB = {qb * q3, qb * q4};
                const f32x2 q44 = {q4, q4};
                const f32x2 dtx2 = {dtx, dtx};
                f32x2 y2 = {0.f, 0.f};
                #pragma unroll
                for (int g = 0; g < 8; ++g) {
                    const f32x4 Bq = *reinterpret_cast<const f32x4*>(&BCs[r][base + g * 4]);
                    const f32x4 Cq = *reinterpret_cast<const f32x4*>(&BCs[r][64 + base + g * 4]);
                    const f32x2 B01 = {Bq[0], Bq[1]};
                    const f32x2 B23 = {Bq[2], Bq[3]};
                    const f32x2 C01 = {Cq[0], Cq[1]};
                    const f32x2 C23 = {Cq[2], Cq[3]};
                    h2[2*g]   = pA * h2[2*g]   + B01 * dtx2;
                    h2[2*g+1] = pB * h2[2*g+1] + B23 * dtx2;
                    y2 = h2[2*g] * C01 + y2;
                    y2 = h2[2*g+1] * C23 + y2;
                    pA = pA * q44; pB = pB * q44;
                }
                float y = y2.x + y2.y;
                const float yt = y + __shfl_xor(y, 1, 64);
                if (half == 0) {
                    const size_t row = bL + t0 + ts + r;
                    xc[row * 2048 + d] = f2bf(fmaf(xv, Dp, yt));
                }
            }
        } else {
            float* hs = (float*)h2;
            for (int r = 0; r < 16; ++r) {
                const float dts = dts_s[r][dl];
                const float xv  = xcs_s[r][dl];
                const float dtx = dts * xv;
                float y = 0.f;
                #pragma unroll
                for (int j = 0; j < 32; ++j) {
                    const float a = __expf(-__expf(A_log[d * DSTATE + base + j]) * dts);
                    hs[j] = fmaf(a, hs[j], dtx * BCs[r][base + j]);
                    y = fmaf(hs[j], BCs[r][64 + base + j], y);
                }
                const float yt = y + __shfl_xor(y, 1, 64);
                if (half == 0) {
                    const size_t row = bL + t0 + ts + r;
                    xc[row * 2048 + d] = f2bf(fmaf(xv, Dp, yt));
                }
            }
        }
    }
}

// ---------------- RMSNorm * norm_w * silu(z), in-place on y ----------------------------
__global__ __launch_bounds__(256) void rms_gate_kernel(
    u16* __restrict__ y, const u16* __restrict__ xz,
    const float* __restrict__ norm_w)
{
    const int row = blockIdx.x;
    const int tid = threadIdx.x;
    const size_t ybase = (size_t)row * DINNER;
    const size_t zbase = (size_t)row * 4096 + DINNER;
    const int i8 = tid * 8;

    float yv[8];
    {
        uint4 u = *reinterpret_cast<const uint4*>(y + ybase + i8);
        yv[0]=bf2f((u16)(u.x&0xffff)); yv[1]=bf2f((u16)(u.x>>16));
        yv[2]=bf2f((u16)(u.y&0xffff)); yv[3]=bf2f((u16)(u.y>>16));
        yv[4]=bf2f((u16)(u.z&0xffff)); yv[5]=bf2f((u16)(u.z>>16));
        yv[6]=bf2f((u16)(u.w&0xffff)); yv[7]=bf2f((u16)(u.w>>16));
    }
    float ss = 0.f;
    #pragma unroll
    for (int j = 0; j < 8; ++j) ss = fmaf(yv[j], yv[j], ss);
    #pragma unroll
    for (int off = 32; off > 0; off >>= 1) ss += __shfl_down(ss, off, 64);
    __shared__ float sred[4];
    const int lane = tid & 63, wid = tid >> 6;
    if (lane == 0) sred[wid] = ss;
    __syncthreads();
    const float tot = sred[0] + sred[1] + sred[2] + sred[3];
    const float scale = rsqrtf(tot * (1.f / (float)DINNER) + 1.1920929e-07f);

    float zv[8];
    {
        uint4 u = *reinterpret_cast<const uint4*>(xz + zbase + i8);
        zv[0]=bf2f((u16)(u.x&0xffff)); zv[1]=bf2f((u16)(u.x>>16));
        zv[2]=bf2f((u16)(u.y&0xffff)); zv[3]=bf2f((u16)(u.y>>16));
        zv[4]=bf2f((u16)(u.z&0xffff)); zv[5]=bf2f((u16)(u.z>>16));
        zv[6]=bf2f((u16)(u.w&0xffff)); zv[7]=bf2f((u16)(u.w>>16));
    }
    float4 n0 = *reinterpret_cast<const float4*>(norm_w + i8);
    float4 n1 = *reinterpret_cast<const float4*>(norm_w + i8 + 4);
    const float nw[8] = {n0.x,n0.y,n0.z,n0.w,n1.x,n1.y,n1.z,n1.w};
    float o[8];
    #pragma unroll
    for (int j = 0; j < 8; ++j) o[j] = yv[j] * scale * nw[j] * silu_f(zv[j]);
    uint4 ov;
    ov.x = pack2(o[0], o[1]); ov.y = pack2(o[2], o[3]);
    ov.z = pack2(o[4], o[5]); ov.w = pack2(o[6], o[7]);
    *reinterpret_cast<uint4*>(y + ybase + i8) = ov;
}

extern "C" void kernel_launch(void* const* d_in, const int* in_sizes, int n_in,
                              void* d_out, int out_size, void* d_ws, size_t ws_size,
                              hipStream_t stream)
{
    const float* x       = (const float*)d_in[0];
    const float* W_in    = (const float*)d_in[1];
    const float* conv_w  = (const float*)d_in[2];
    const float* conv_b  = (const float*)d_in[3];
    const float* W_x     = (const float*)d_in[4];
    const float* W_dt    = (const float*)d_in[5];
    const float* b_dt    = (const float*)d_in[6];
    const float* A_log   = (const float*)d_in[7];
    const float* D_param = (const float*)d_in[8];
    const float* W_out   = (const float*)d_in[9];
    const float* norm_w  = (const float*)d_in[10];
    float* out = (float*)d_out;

    hipFuncSetAttribute(reinterpret_cast<const void*>(&gemm256<u16, 0>),
                        hipFuncAttributeMaxDynamicSharedMemorySize, 131072);
    hipFuncSetAttribute(reinterpret_cast<const void*>(&gemm256<u16, 2>),
                        hipFuncAttributeMaxDynamicSharedMemorySize, 131072);
    hipFuncSetAttribute(reinterpret_cast<const void*>(&gemm256<float, 0>),
                        hipFuncAttributeMaxDynamicSharedMemorySize, 131072);

    // ---- workspace layout (bytes) ----
    char* ws = (char*)d_ws;
    u16* xz  = (u16*)(ws);                   // 8192 x 4096 bf16 (x_ssm | z)
    u16* xc  = (u16*)(ws + 67108864ull);     // 8192 x 2048 bf16 (x_conv, then y)
    u16* dbc = (u16*)(ws + 100663296ull);    // 8192 x 2304 bf16 [B | C | sp(dt) | pad]
    u16* xbf  = dbc;                         // x bf16 scratch (dead before dbc written)
    u16* Wxbf = xz;                          // W_x bf16 scratch (dead before xz written)
    u16* Wt_out = (u16*)(ws + 138412032ull); // 1024 x 2048 bf16
    float* bias2304 = (float*)(ws + 142606336ull);      // 2304 fp32
    float* A0f = (float*)(ws + 142615552ull);           // 2048 fp32
    unsigned char* okf = (unsigned char*)(ws + 142623744ull); // 2048 u8
    const size_t fixed_bytes = 142625792ull;
    const size_t per_chunk = 2ull * DSTATE * DINNER * 4 + 2ull * DINNER * 4; // 1,064,960
    int nchunk = 32;
    while (nchunk > 1 && fixed_bytes + (size_t)nchunk * per_chunk > ws_size) nchunk >>= 1;
    const int chunk = L_SEQ / nchunk;
    float* hbuf = (float*)(ws + fixed_bytes);
    float* sdt  = (float*)(ws + fixed_bytes + (size_t)nchunk * 2ull * DSTATE * DINNER * 4);

    u16* Wt_in = (u16*)d_out;                // 4096 x 1024 (d_out scratch, dead by final GEMM)
    u16* Wt_x  = Wt_in + 4194304ull;         // 2304 x 2048: [B|C]^T rows 0..127, WcombT 128..2175, pad
    u16* Wt_dt = Wt_x + 4718592ull;          // 2048 x 2048

    const int M = NROWS; // 8192

    // 0) converts / transposes / bias / A0 precompute / pad-zero
    f32_to_bf16_kernel<<<(M * DMODEL) / 1024, 256, 0, stream>>>(x, xbf);
    f32_to_bf16_kernel<<<(DINNER * 2176) / 1024, 256, 0, stream>>>(W_x, Wxbf);
    transpose_bf16_kernel<<<dim3(4096 / 32, 1024 / 32), 256, 0, stream>>>(W_in, Wt_in, 1024, 4096);
    transpose_bf16_kernel<<<dim3(4, 2048 / 32), 256, 0, stream>>>(W_x, Wt_x, 2048, 2176); // cols 0..127
    transpose_bf16_kernel<<<dim3(2048 / 32, 2048 / 32), 256, 0, stream>>>(W_dt, Wt_dt, 2048, 2048);
    transpose_bf16_kernel<<<dim3(1024 / 32, 2048 / 32), 256, 0, stream>>>(W_out, Wt_out, 2048, 1024);
    bias_cat_kernel<<<9, 256, 0, stream>>>(b_dt, bias2304);
    a0_kernel<<<DINNER / 256, 256, 0, stream>>>(A_log, A0f, okf);
    hipMemsetAsync(Wt_x + 2176ull * 2048, 0, 128ull * 2048 * 2, stream);  // pad rows
    // 0b) WcombT = W_dt^T @ W_x[:,128:]^T -> Wt_x rows 128..2175   [128^2: 256 wgs = 1/CU]
    mfma_gemm<u16><<<dim3(2048 / 128, 2048 / 128), 256, 0, stream>>>(
        Wt_dt, 2048, Wxbf + 128, 2176, Wt_x + 128ull * 2048, 2048, 2048, nullptr);

    // 1) xz = x @ W_in                                  [256^2 8-phase]
    gemm256<u16, 0><<<dim3(4096 / 256, M / 256), 512, 131072, stream>>>(
        xbf, DMODEL, Wt_in, DMODEL, xz, 4096, DMODEL, nullptr);
    // 2) xc = silu(causal_dwconv(x_ssm) + conv_b)
    conv_silu_kernel<<<(M * DINNER) / (256 * 8), 256, 0, stream>>>(xz, conv_w, conv_b, xc);
    // 3) dbc = xc @ [W_x[:,:128] | Wcomb | pad] + bias; softplus on cols>=128  [256^2]
    gemm256<u16, 2><<<dim3(DBCS / 256, M / 256), 512, 131072, stream>>>(
        xc, DINNER, Wt_x, DINNER, dbc, DBCS, DINNER, bias2304);
    // 4-6) chunked selective scan
    scan_phase1<<<dim3(DINNER / DPB, nchunk, NB), 256, 0, stream>>>(
        xc, dbc, A_log, A0f, okf, hbuf, sdt, nchunk, chunk);
    scan_phase2<<<(NB * DINNER * DSTATE) / 256, 256, 0, stream>>>(hbuf, sdt, A_log, nchunk);
    scan_phase3<<<dim3(DINNER / DPB, nchunk, NB), 256, 0, stream>>>(
        xc, dbc, A_log, A0f, okf, hbuf, D_param, nchunk, chunk);
    // 7) y = rmsnorm(y) * norm_w * silu(z)
    rms_gate_kernel<<<M, 256, 0, stream>>>(xc, xz, norm_w);
    // 8) out = y @ W_out                                [256^2 8-phase, fp32 out]
    gemm256<float, 0><<<dim3(1024 / 256, M / 256), 512, 131072, stream>>>(
        xc, DINNER, Wt_out, DINNER, out, DMODEL, DINNER, nullptr);
}